// Round 2
// baseline (418.847 us; speedup 1.0000x reference)
//
#include <hip/hip_runtime.h>

#define NN 2048
#define DD 128

typedef _Float16 f16x4 __attribute__((ext_vector_type(4)));
typedef _Float16 f16x8 __attribute__((ext_vector_type(8)));
typedef float f32x4 __attribute__((ext_vector_type(4)));

// ---------------------------------------------------------------------------
// gemmY: Yt[b][d][n] = sum_k X[b][n][k] * W[k][d]   (K = 128, fp32 in, fp16 out)
// A = W^T (LDS, fp16), B = X rows (k-contiguous). Output transposed so agg
// reads k-contiguous A rows.
// ---------------------------------------------------------------------------
__global__ __launch_bounds__(256) void gemmY_kernel(
    const float* __restrict__ Xin,   // [B][NN][128] fp32
    const float* __restrict__ W,     // [128][128] row-major (k, dout)
    _Float16* __restrict__ Yt)       // [B][128][NN]
{
  __shared__ _Float16 Ws[128][136];  // [dout][k], k in [0,128) + pad  (BUG FIX: was [72])
  __shared__ _Float16 Xs[64][136];   // [n][k]
  const int tid = threadIdx.x;
  const int bx = blockIdx.x;
  const int batch = bx & 7;          // XCD-friendly: one batch per XCD
  const int n0 = (bx >> 3) * 64;

  // stage W^T fp32 -> fp16
#pragma unroll
  for (int u = 0; u < 16; ++u) {
    int c = tid + 256 * u;           // 4096 float4s of W
    int k = c >> 5, d4 = (c & 31) * 4;
    float4 wv = *(const float4*)(W + k * 128 + d4);
    Ws[d4 + 0][k] = (_Float16)wv.x;
    Ws[d4 + 1][k] = (_Float16)wv.y;
    Ws[d4 + 2][k] = (_Float16)wv.z;
    Ws[d4 + 3][k] = (_Float16)wv.w;
  }
  const float* Xp = Xin + (size_t)(batch * NN + n0) * DD;
#pragma unroll
  for (int u = 0; u < 8; ++u) {
    int c = tid + 256 * u;           // 2048 float4s
    int n = c >> 5, f4 = (c & 31) * 4;
    float4 xv = *(const float4*)(Xp + (size_t)n * DD + f4);
    f16x4 hv = {(_Float16)xv.x, (_Float16)xv.y, (_Float16)xv.z, (_Float16)xv.w};
    *(f16x4*)&Xs[n][f4] = hv;
  }
  __syncthreads();

  const int lane = tid & 63, wave = tid >> 6;
  const int quad = lane >> 4, l15 = lane & 15;
  const int d0 = wave * 32;
  f32x4 acc[2][4] = {};
#pragma unroll
  for (int kk = 0; kk < 128; kk += 32) {
    f16x8 a0 = *(const f16x8*)&Ws[d0 + l15][kk + quad * 8];
    f16x8 a1 = *(const f16x8*)&Ws[d0 + 16 + l15][kk + quad * 8];
#pragma unroll
    for (int fi = 0; fi < 4; ++fi) {
      f16x8 b = *(const f16x8*)&Xs[fi * 16 + l15][kk + quad * 8];
      acc[0][fi] = __builtin_amdgcn_mfma_f32_16x16x32_f16(a0, b, acc[0][fi], 0, 0, 0);
      acc[1][fi] = __builtin_amdgcn_mfma_f32_16x16x32_f16(a1, b, acc[1][fi], 0, 0, 0);
    }
  }
  // D frag: row(dout) = quad*4 + r, col(n) = lane&15
  _Float16* YtB = Yt + (size_t)batch * DD * NN;
#pragma unroll
  for (int df = 0; df < 2; ++df)
#pragma unroll
    for (int fi = 0; fi < 4; ++fi)
#pragma unroll
      for (int r = 0; r < 4; ++r) {
        int d = d0 + df * 16 + quad * 4 + r;
        int n = n0 + fi * 16 + l15;
        YtB[(size_t)d * NN + n] = (_Float16)acc[df][fi][r];
      }
}

// ---------------------------------------------------------------------------
// agg: Zt[d][i] = sum_j Yt[d][j] * adj[i][j]
//      out[i][d] = relu((Zt[d][i] + bias[d]) / (rowsum(adj[i]) + 1))
// rowsum computed for free during the adj traversal (every layer).
// Block = 64 rows (i) x 128 cols (d); grid 256 = 1 block/CU.
// ---------------------------------------------------------------------------
__global__ __launch_bounds__(256) void agg_kernel(
    const float* __restrict__ adj,       // [B][NN][NN] fp32
    const _Float16* __restrict__ Yt,     // [B][128][NN]
    const float* __restrict__ bias,      // [128]
    float* __restrict__ out)             // [B][NN][128] fp32
{
  __shared__ __align__(16) char smem[33792];
  _Float16 (*As)[72] = (_Float16(*)[72])smem;            // [128][72] Yt tile
  _Float16 (*Bs)[72] = (_Float16(*)[72])(smem + 18432);  // [64][72]  adj tile
  float    (*Xs32)[132] = (float(*)[132])smem;           // epilogue reuse
  __shared__ float bsh[128];
  __shared__ float rd[64];

  const int tid = threadIdx.x;
  const int bx = blockIdx.x;
  const int batch = bx & 7;          // XCD-friendly: one batch per XCD
  const int i0 = (bx >> 3) * 64;
  const int lane = tid & 63, wave = tid >> 6;
  const int quad = lane >> 4, l15 = lane & 15;
  const int ai = tid >> 2, aq = tid & 3;   // adj staging: 4 threads/row

  const float* adjB = adj + (size_t)(batch * NN + i0) * NN;
  const _Float16* YtB = Yt + (size_t)batch * DD * NN;

  if (tid < 128) bsh[tid] = bias[tid];

  f32x4 acc[2][4] = {};
  float rowsum = 0.0f;

  float4 av[4];
  uint4 yv[4];
  // prefetch tile 0
#pragma unroll
  for (int u = 0; u < 4; ++u)
    av[u] = *(const float4*)(adjB + (size_t)ai * NN + (aq + 4 * u) * 4);
#pragma unroll
  for (int u = 0; u < 4; ++u) {
    int c = tid + 256 * u;
    int dd = c >> 3, h = (c & 7) * 8;
    yv[u] = *(const uint4*)(YtB + (size_t)dd * NN + h);
  }

  const int d0 = wave * 32;
  for (int ko = 0; ko < NN / 64; ++ko) {
    __syncthreads();
    // store current tile to LDS (adj -> fp16; fold in row sums, fp32-exact)
#pragma unroll
    for (int u = 0; u < 4; ++u) {
      float4 v = av[u];
      rowsum += (v.x + v.y) + (v.z + v.w);
      f16x4 hv = {(_Float16)v.x, (_Float16)v.y, (_Float16)v.z, (_Float16)v.w};
      *(f16x4*)&Bs[ai][(aq + 4 * u) * 4] = hv;
    }
#pragma unroll
    for (int u = 0; u < 4; ++u) {
      int c = tid + 256 * u;
      int dd = c >> 3, h = (c & 7) * 8;
      *(uint4*)&As[dd][h] = yv[u];
    }
    __syncthreads();
    // software prefetch next tile (overlaps with MFMA below)
    if (ko + 1 < NN / 64) {
      const int kb = (ko + 1) * 64;
#pragma unroll
      for (int u = 0; u < 4; ++u)
        av[u] = *(const float4*)(adjB + (size_t)ai * NN + kb + (aq + 4 * u) * 4);
#pragma unroll
      for (int u = 0; u < 4; ++u) {
        int c = tid + 256 * u;
        int dd = c >> 3, h = (c & 7) * 8;
        yv[u] = *(const uint4*)(YtB + (size_t)dd * NN + kb + h);
      }
    }
#pragma unroll
    for (int kk = 0; kk < 64; kk += 32) {
      f16x8 a0 = *(const f16x8*)&As[d0 + l15][kk + quad * 8];
      f16x8 a1 = *(const f16x8*)&As[d0 + 16 + l15][kk + quad * 8];
#pragma unroll
      for (int fi = 0; fi < 4; ++fi) {
        f16x8 b = *(const f16x8*)&Bs[fi * 16 + l15][kk + quad * 8];
        acc[0][fi] = __builtin_amdgcn_mfma_f32_16x16x32_f16(a0, b, acc[0][fi], 0, 0, 0);
        acc[1][fi] = __builtin_amdgcn_mfma_f32_16x16x32_f16(a1, b, acc[1][fi], 0, 0, 0);
      }
    }
  }

  // reduce 4 partial row sums (threads 4i..4i+3 are consecutive same-wave lanes)
  rowsum += __shfl_xor(rowsum, 1);
  rowsum += __shfl_xor(rowsum, 2);
  if (aq == 0) rd[ai] = 1.0f / (rowsum + 1.0f);
  __syncthreads();   // rd ready; all LDS frag reads done before smem reuse

  // epilogue: bias + scale + relu, transpose Zt[d][i] -> out[i][d] via LDS
#pragma unroll
  for (int df = 0; df < 2; ++df)
#pragma unroll
    for (int fi = 0; fi < 4; ++fi)
#pragma unroll
      for (int r = 0; r < 4; ++r) {
        int d = d0 + df * 16 + quad * 4 + r;
        int i = fi * 16 + l15;
        float v = (acc[df][fi][r] + bsh[d]) * rd[i];
        Xs32[i][d] = fmaxf(v, 0.0f);
      }
  __syncthreads();
  float* outB = out + (size_t)(batch * NN + i0) * DD;
#pragma unroll
  for (int u = 0; u < 8; ++u) {
    int c = tid + 256 * u;             // 2048 float4s
    int i = c >> 5, f4 = (c & 31) * 4;
    *(float4*)(outB + (size_t)i * DD + f4) = *(const float4*)&Xs32[i][f4];
  }
}

extern "C" void kernel_launch(void* const* d_in, const int* in_sizes, int n_in,
                              void* d_out, int out_size, void* d_ws, size_t ws_size,
                              hipStream_t stream) {
  const float* x0   = (const float*)d_in[0];   // [8,2048,128]
  const float* adj  = (const float*)d_in[1];   // [8,2048,2048]
  const float* W    = (const float*)d_in[2];   // [3,128,128]
  const float* bias = (const float*)d_in[3];   // [3,128]
  float* out = (float*)d_out;

  _Float16* Yt = (_Float16*)d_ws;    // 8*128*2048 fp16 = 4 MiB (only ws use)
  // Inter-layer activations live in d_out (fp32, fully overwritten by the
  // final agg) — keeps ws usage minimal and activations at full precision.

  dim3 grid(256), blk(256);
  // layer 1
  gemmY_kernel<<<grid, blk, 0, stream>>>(x0,  W,         Yt);
  agg_kernel  <<<grid, blk, 0, stream>>>(adj, Yt, bias,       out);
  // layer 2
  gemmY_kernel<<<grid, blk, 0, stream>>>(out, W + 16384, Yt);
  agg_kernel  <<<grid, blk, 0, stream>>>(adj, Yt, bias + 128, out);
  // layer 3
  gemmY_kernel<<<grid, blk, 0, stream>>>(out, W + 32768, Yt);
  agg_kernel  <<<grid, blk, 0, stream>>>(adj, Yt, bias + 256, out);
}

// Round 3
// 290.772 us; speedup vs baseline: 1.4405x; 1.4405x over previous
//
#include <hip/hip_runtime.h>

#define NN 2048
#define DD 128

typedef _Float16 f16x8 __attribute__((ext_vector_type(8)));
typedef float f32x4 __attribute__((ext_vector_type(4)));

// ---------------------------------------------------------------------------
// prep: Wt[l][d][k] = fp16(W[l][k][d])  (3 layers, 48K elems — trivial)
// ---------------------------------------------------------------------------
__global__ __launch_bounds__(256) void prep_kernel(
    const float* __restrict__ W, _Float16* __restrict__ Wt) {
  int idx = blockIdx.x * 256 + threadIdx.x;
  int l = idx >> 14, r = idx & 16383, d = r >> 7, k = r & 127;
  Wt[idx] = (_Float16)W[l * 16384 + k * 128 + d];
}

// ---------------------------------------------------------------------------
// gemmY (layer 0 only): Yt[b][d][n] = sum_k X[b][n][k] * W0[k][d]
// LDS-free: A (Wt fp16) and B (X fp32, cvt in regs) straight from global.
// No barriers; waves fully independent. 512 blocks (32-row n-tiles).
// ---------------------------------------------------------------------------
__global__ __launch_bounds__(256) void gemmY_kernel(
    const float* __restrict__ X, const _Float16* __restrict__ Wt,
    _Float16* __restrict__ Yt) {
  const int bx = blockIdx.x;
  const int batch = bx & 7, n0 = (bx >> 3) * 32;
  const int tid = threadIdx.x, lane = tid & 63, wave = tid >> 6;
  const int quad = lane >> 4, l15 = lane & 15, d0 = wave * 32;
  const float* Xb = X + (size_t)(batch * NN + n0) * DD;
  f32x4 acc[2][2] = {};
#pragma unroll
  for (int kk = 0; kk < 128; kk += 32) {
    f16x8 a0 = *(const f16x8*)(Wt + (d0 + l15) * DD + kk + quad * 8);
    f16x8 a1 = *(const f16x8*)(Wt + (d0 + 16 + l15) * DD + kk + quad * 8);
#pragma unroll
    for (int fi = 0; fi < 2; ++fi) {
      const float* xp = Xb + (size_t)(fi * 16 + l15) * DD + kk + quad * 8;
      float4 x0 = *(const float4*)xp;
      float4 x1 = *(const float4*)(xp + 4);
      f16x8 b = {(_Float16)x0.x, (_Float16)x0.y, (_Float16)x0.z, (_Float16)x0.w,
                 (_Float16)x1.x, (_Float16)x1.y, (_Float16)x1.z, (_Float16)x1.w};
      acc[0][fi] = __builtin_amdgcn_mfma_f32_16x16x32_f16(a0, b, acc[0][fi], 0, 0, 0);
      acc[1][fi] = __builtin_amdgcn_mfma_f32_16x16x32_f16(a1, b, acc[1][fi], 0, 0, 0);
    }
  }
  _Float16* YtB = Yt + (size_t)batch * DD * NN;
#pragma unroll
  for (int df = 0; df < 2; ++df)
#pragma unroll
    for (int fi = 0; fi < 2; ++fi)
#pragma unroll
      for (int r = 0; r < 4; ++r)
        YtB[(size_t)(d0 + df * 16 + quad * 4 + r) * NN + n0 + fi * 16 + l15] =
            (_Float16)acc[df][fi][r];
}

// ---------------------------------------------------------------------------
// agg: Zt[d][i] = sum_j Yt[d][j]*adj[i][j]; act = relu((Z+b)*1/(rowsum+1))
// A-frags (Yt fp16) from GLOBAL with 1-tile register prefetch (no LDS).
// B (adj) via XOR-swizzled double-buffered LDS (one barrier per k-tile).
// !LAST: epilogue fuses next layer's Linear: Ytn[d][i] = (act @ Wn)^T.
// LAST:  writes fp32 activations to out.
// 512 blocks (32 i x 128 d), 2 blocks/CU.
// ---------------------------------------------------------------------------
template<bool LAST>
__global__ __launch_bounds__(256) void agg_kernel(
    const float* __restrict__ adj, const _Float16* __restrict__ Yt,
    const float* __restrict__ bias, const _Float16* __restrict__ Wn,
    _Float16* __restrict__ Ytn, float* __restrict__ out) {
  __shared__ _Float16 Bs[2][32 * 64];   // swizzled flat, 2 x 4 KB
  __shared__ float Xs[32][132];         // epilogue activation tile
  __shared__ float bsh[128];
  __shared__ float rd[32];

  const int tid = threadIdx.x, bx = blockIdx.x;
  const int batch = bx & 7, i0 = (bx >> 3) * 32;
  const int lane = tid & 63, wave = tid >> 6;
  const int quad = lane >> 4, l15 = lane & 15, d0 = wave * 32;
  const int ai = tid >> 3, ac = tid & 7;       // adj staging: 8 thr/row, 1 chunk ea
  const int sc = ac ^ (ai & 7);                // swizzled 16-B chunk slot

  const float* adjR = adj + (size_t)(batch * NN + i0 + ai) * NN + ac * 8;
  const _Float16* YtB = Yt + (size_t)batch * DD * NN;
  const _Float16* Ya0 = YtB + (size_t)(d0 + l15) * NN;
  const _Float16* Ya1 = YtB + (size_t)(d0 + 16 + l15) * NN;

  if (tid < 128) bsh[tid] = bias[tid];

  f32x4 acc[2][2] = {};
  float rowsum = 0.f;

  // prefetch tile 0: adj (2 float4 = one 16-B fp16 chunk) + 4 A-frags
  float4 av0 = *(const float4*)(adjR);
  float4 av1 = *(const float4*)(adjR + 4);
  f16x8 a[2][2];
#pragma unroll
  for (int k2 = 0; k2 < 2; ++k2) {
    a[k2][0] = *(const f16x8*)(Ya0 + k2 * 32 + quad * 8);
    a[k2][1] = *(const f16x8*)(Ya1 + k2 * 32 + quad * 8);
  }

  for (int ko = 0; ko < 32; ++ko) {
    // convert + swizzled store (uniform bank spread), fold row sums (fp32)
    rowsum += ((av0.x + av0.y) + (av0.z + av0.w)) + ((av1.x + av1.y) + (av1.z + av1.w));
    f16x8 h = {(_Float16)av0.x, (_Float16)av0.y, (_Float16)av0.z, (_Float16)av0.w,
               (_Float16)av1.x, (_Float16)av1.y, (_Float16)av1.z, (_Float16)av1.w};
    *(f16x8*)(&Bs[ko & 1][ai * 64 + sc * 8]) = h;
    f16x8 an[2][2];
    if (ko < 31) {  // prefetch next tile (lands during this tile's MFMA)
      const int kb = (ko + 1) * 64;
      av0 = *(const float4*)(adjR + kb);
      av1 = *(const float4*)(adjR + kb + 4);
#pragma unroll
      for (int k2 = 0; k2 < 2; ++k2) {
        an[k2][0] = *(const f16x8*)(Ya0 + kb + k2 * 32 + quad * 8);
        an[k2][1] = *(const f16x8*)(Ya1 + kb + k2 * 32 + quad * 8);
      }
    }
    __syncthreads();   // single barrier: double-buffered Bs covers WAR
    const _Float16* B = Bs[ko & 1];
#pragma unroll
    for (int k2 = 0; k2 < 2; ++k2)
#pragma unroll
      for (int fi = 0; fi < 2; ++fi) {
        const int row = fi * 16 + l15;
        const int ch = (k2 * 4 + quad) ^ (row & 7);
        f16x8 b = *(const f16x8*)(&B[row * 64 + ch * 8]);
        acc[0][fi] = __builtin_amdgcn_mfma_f32_16x16x32_f16(a[k2][0], b, acc[0][fi], 0, 0, 0);
        acc[1][fi] = __builtin_amdgcn_mfma_f32_16x16x32_f16(a[k2][1], b, acc[1][fi], 0, 0, 0);
      }
#pragma unroll
    for (int k2 = 0; k2 < 2; ++k2) { a[k2][0] = an[k2][0]; a[k2][1] = an[k2][1]; }
  }

  // row-sum reduce across the 8 staging lanes of each row (same wave)
  rowsum += __shfl_xor(rowsum, 1);
  rowsum += __shfl_xor(rowsum, 2);
  rowsum += __shfl_xor(rowsum, 4);
  if (ac == 0) rd[ai] = 1.0f / (rowsum + 1.0f);
  __syncthreads();

  // activation tile: relu((Z+b)*rd), transposed into Xs[i][d]
#pragma unroll
  for (int df = 0; df < 2; ++df)
#pragma unroll
    for (int fi = 0; fi < 2; ++fi)
#pragma unroll
      for (int r = 0; r < 4; ++r) {
        int d = d0 + df * 16 + quad * 4 + r;
        int i = fi * 16 + l15;
        Xs[i][d] = fmaxf((acc[df][fi][r] + bsh[d]) * rd[i], 0.f);
      }
  __syncthreads();

  if (LAST) {
    float* outB = out + (size_t)(batch * NN + i0) * DD;
#pragma unroll
    for (int u = 0; u < 4; ++u) {
      int c = tid + 256 * u;
      int i = c >> 5, f4 = (c & 31) * 4;
      *(float4*)(outB + (size_t)i * DD + f4) = *(const float4*)&Xs[i][f4];
    }
  } else {
    // fused next-layer Linear: Ytn[d][i0+i] = sum_k Xs[i][k] * Wn[k][d]
    f32x4 acc2[2][2] = {};
#pragma unroll
    for (int kk = 0; kk < 128; kk += 32) {
      f16x8 a0 = *(const f16x8*)(Wn + (d0 + l15) * DD + kk + quad * 8);
      f16x8 a1 = *(const f16x8*)(Wn + (d0 + 16 + l15) * DD + kk + quad * 8);
#pragma unroll
      for (int fi = 0; fi < 2; ++fi) {
        const float* xp = &Xs[fi * 16 + l15][kk + quad * 8];
        f16x8 b = {(_Float16)xp[0], (_Float16)xp[1], (_Float16)xp[2], (_Float16)xp[3],
                   (_Float16)xp[4], (_Float16)xp[5], (_Float16)xp[6], (_Float16)xp[7]};
        acc2[0][fi] = __builtin_amdgcn_mfma_f32_16x16x32_f16(a0, b, acc2[0][fi], 0, 0, 0);
        acc2[1][fi] = __builtin_amdgcn_mfma_f32_16x16x32_f16(a1, b, acc2[1][fi], 0, 0, 0);
      }
    }
    _Float16* YnB = Ytn + (size_t)batch * DD * NN;
#pragma unroll
    for (int df = 0; df < 2; ++df)
#pragma unroll
      for (int fi = 0; fi < 2; ++fi)
#pragma unroll
        for (int r = 0; r < 4; ++r)
          YnB[(size_t)(d0 + df * 16 + quad * 4 + r) * NN + i0 + fi * 16 + l15] =
              (_Float16)acc2[df][fi][r];
  }
}

extern "C" void kernel_launch(void* const* d_in, const int* in_sizes, int n_in,
                              void* d_out, int out_size, void* d_ws, size_t ws_size,
                              hipStream_t stream) {
  const float* x0   = (const float*)d_in[0];   // [8,2048,128]
  const float* adj  = (const float*)d_in[1];   // [8,2048,2048]
  const float* W    = (const float*)d_in[2];   // [3,128,128]
  const float* bias = (const float*)d_in[3];   // [3,128]
  float* out = (float*)d_out;

  _Float16* Wt   = (_Float16*)d_ws;                    // 96 KB fp16 W^T x3
  _Float16* YtA  = (_Float16*)((char*)d_ws + 131072);  // 4 MiB
  _Float16* YtB_ = (_Float16*)d_out;                   // d_out doubles as 4 MiB f16 scratch

  dim3 blk(256);
  prep_kernel <<<192, blk, 0, stream>>>(W, Wt);
  gemmY_kernel<<<512, blk, 0, stream>>>(x0, Wt, YtA);
  // layer 1 agg (+ fused layer-2 Linear)
  agg_kernel<false><<<512, blk, 0, stream>>>(adj, YtA,  bias,       Wt + 16384, YtB_, nullptr);
  // layer 2 agg (+ fused layer-3 Linear)
  agg_kernel<false><<<512, blk, 0, stream>>>(adj, YtB_, bias + 128, Wt + 32768, YtA,  nullptr);
  // layer 3 agg -> final fp32 output
  agg_kernel<true ><<<512, blk, 0, stream>>>(adj, YtA,  bias + 256, nullptr,    nullptr, out);
}